// Round 1
// baseline (136.897 us; speedup 1.0000x reference)
//
#include <hip/hip_runtime.h>
#include <hip/hip_bf16.h>

#define N_ENT 100000
#define NB 16
#define DIM 128
#define TILE_E 32
#define PAD 132          // 128 + 4 floats: breaks LDS bank aliasing, keeps 16B align
#define N_TILES (N_ENT / TILE_E)   // 3125 exact

// ---------------- kernel 1: head = normalize(ent[e1]) + normalize(rel[r]) ----
__global__ __launch_bounds__(128) void head_kernel(
    const int* __restrict__ e1, const int* __restrict__ rel,
    const float* __restrict__ ent, const float* __restrict__ relemb,
    float* __restrict__ head)
{
    int b = blockIdx.x, d = threadIdx.x;
    float ev = ent[e1[b] * DIM + d];
    float rv = relemb[rel[b] * DIM + d];
    __shared__ float s1[DIM], s2[DIM];
    s1[d] = ev * ev;
    s2[d] = rv * rv;
    __syncthreads();
    for (int s = 64; s > 0; s >>= 1) {
        if (d < s) { s1[d] += s1[d + s]; s2[d] += s2[d + s]; }
        __syncthreads();
    }
    float ne = fmaxf(sqrtf(s1[0]), 1e-12f);
    float nr = fmaxf(sqrtf(s2[0]), 1e-12f);
    head[b * DIM + d] = ev / ne + rv / nr;
}

// ---------------- kernel 2: dist[b,n] = sum_d |head[b,d] - ent[n,d]/||ent[n]|| |
// also per-row global max via int atomicMax (dist >= 0)
__global__ __launch_bounds__(256) void dist_kernel(
    const float* __restrict__ ent, const float* __restrict__ head,
    int* __restrict__ rowmax, float* __restrict__ out)
{
    __shared__ float ldsH[NB * PAD];        // 8448 B
    __shared__ float ldsN[TILE_E * PAD];    // 16896 B (also reused as scratch)
    __shared__ float ldsinv[TILE_E];

    const int tid = threadIdx.x;
    const int b  = tid & 15;
    const int eg = tid >> 4;

    // stage head once (512 float4)
    for (int k = tid; k < NB * DIM / 4; k += 256) {
        int r = k >> 5, c = k & 31;
        float4 v = ((const float4*)head)[r * 32 + c];
        *(float4*)&ldsH[r * PAD + c * 4] = v;
    }

    float bmax = 0.f;

    for (int tile = blockIdx.x; tile < N_TILES; tile += gridDim.x) {
        __syncthreads();   // protect LDS reuse from previous iteration / head staging
        // stage node tile (1024 float4, coalesced)
        for (int k = tid; k < TILE_E * DIM / 4; k += 256) {
            int r = k >> 5, c = k & 31;
            float4 v = ((const float4*)ent)[(tile * TILE_E + r) * 32 + c];
            *(float4*)&ldsN[r * PAD + c * 4] = v;
        }
        __syncthreads();

        // per-row inv norms: 8 threads per row, 16 floats each
        {
            int r = tid >> 3, k = tid & 7;
            const float* p = &ldsN[r * PAD + k * 16];
            float s = 0.f;
            #pragma unroll
            for (int j = 0; j < 16; j += 4) {
                float4 v = *(const float4*)&p[j];
                s += v.x * v.x + v.y * v.y + v.z * v.z + v.w * v.w;
            }
            s += __shfl_down(s, 4);
            s += __shfl_down(s, 2);
            s += __shfl_down(s, 1);
            if (k == 0) ldsinv[r] = 1.0f / fmaxf(sqrtf(s), 1e-12f);
        }
        __syncthreads();

        const float inv0 = ldsinv[eg];
        const float inv1 = ldsinv[eg + 16];
        const float* hp = &ldsH[b * PAD];
        const float* n0 = &ldsN[eg * PAD];
        const float* n1 = &ldsN[(eg + 16) * PAD];
        float acc0 = 0.f, acc1 = 0.f;
        #pragma unroll
        for (int j = 0; j < DIM; j += 4) {
            float4 h = *(const float4*)&hp[j];
            float4 a = *(const float4*)&n0[j];
            float4 c = *(const float4*)&n1[j];
            acc0 += fabsf(fmaf(-a.x, inv0, h.x)) + fabsf(fmaf(-a.y, inv0, h.y))
                  + fabsf(fmaf(-a.z, inv0, h.z)) + fabsf(fmaf(-a.w, inv0, h.w));
            acc1 += fabsf(fmaf(-c.x, inv1, h.x)) + fabsf(fmaf(-c.y, inv1, h.y))
                  + fabsf(fmaf(-c.z, inv1, h.z)) + fabsf(fmaf(-c.w, inv1, h.w));
        }
        bmax = fmaxf(bmax, fmaxf(acc0, acc1));

        __syncthreads();   // compute done -> safe to reuse ldsN as dist scratch
        // transpose dists through LDS for coalesced global writes
        ldsN[b * 33 + eg]      = acc0;
        ldsN[b * 33 + eg + 16] = acc1;
        __syncthreads();
        {
            int ob = tid >> 4, oe = (tid & 15) * 2;
            float2 v = make_float2(ldsN[ob * 33 + oe], ldsN[ob * 33 + oe + 1]);
            *(float2*)&out[ob * N_ENT + tile * TILE_E + oe] = v;
        }
    }

    // block-level per-b max -> one atomic per b per block
    __syncthreads();
    ldsN[eg * 17 + b] = bmax;
    __syncthreads();
    if (tid < 16) {
        float m = 0.f;
        for (int g = 0; g < 16; g++) m = fmaxf(m, ldsN[g * 17 + tid]);
        atomicMax(&rowmax[tid], __float_as_int(m));   // dist >= 0: int order == float order
    }
}

// ---------------- kernel 3: out = exp(dist - rowmax[b]); rowsum[b] += partial --
__global__ __launch_bounds__(256) void exp_kernel(
    float* __restrict__ out, const int* __restrict__ rowmax,
    float* __restrict__ rowsum)
{
    const int b = blockIdx.y;
    const float m = __int_as_float(rowmax[b]);
    float local = 0.f;
    float4* row = (float4*)&out[b * N_ENT];
    const int nv = N_ENT / 4;   // 25000
    for (int i = blockIdx.x * blockDim.x + threadIdx.x; i < nv; i += gridDim.x * blockDim.x) {
        float4 v = row[i];
        v.x = expf(v.x - m); v.y = expf(v.y - m);
        v.z = expf(v.z - m); v.w = expf(v.w - m);
        row[i] = v;
        local += v.x + v.y + v.z + v.w;
    }
    // block reduce
    for (int off = 32; off > 0; off >>= 1) local += __shfl_down(local, off);
    __shared__ float red[4];
    if ((threadIdx.x & 63) == 0) red[threadIdx.x >> 6] = local;
    __syncthreads();
    if (threadIdx.x == 0) {
        atomicAdd(&rowsum[b], red[0] + red[1] + red[2] + red[3]);
    }
}

// ---------------- kernel 4: out *= 1/rowsum[b] ------------------------------
__global__ __launch_bounds__(256) void scale_kernel(
    float* __restrict__ out, const float* __restrict__ rowsum)
{
    const int b = blockIdx.y;
    const float inv = 1.0f / rowsum[b];
    float4* row = (float4*)&out[b * N_ENT];
    const int nv = N_ENT / 4;
    for (int i = blockIdx.x * blockDim.x + threadIdx.x; i < nv; i += gridDim.x * blockDim.x) {
        float4 v = row[i];
        v.x *= inv; v.y *= inv; v.z *= inv; v.w *= inv;
        row[i] = v;
    }
}

extern "C" void kernel_launch(void* const* d_in, const int* in_sizes, int n_in,
                              void* d_out, int out_size, void* d_ws, size_t ws_size,
                              hipStream_t stream) {
    const int*   e1     = (const int*)d_in[0];
    const int*   rel    = (const int*)d_in[1];
    const float* ent    = (const float*)d_in[4];
    const float* relemb = (const float*)d_in[5];
    float* out = (float*)d_out;

    float* head   = (float*)d_ws;                        // 16*128 f32 = 8192 B
    int*   rowmax = (int*)((char*)d_ws + 8192);          // 16 * 4 B
    float* rowsum = (float*)((char*)d_ws + 8192 + 64);   // 16 * 4 B

    // ws is poisoned 0xAA before every timed launch -> zero the accumulators
    hipMemsetAsync((char*)d_ws + 8192, 0, 128, stream);

    head_kernel<<<16, 128, 0, stream>>>(e1, rel, ent, relemb, head);
    dist_kernel<<<1024, 256, 0, stream>>>(ent, head, rowmax, out);
    exp_kernel<<<dim3(64, 16), 256, 0, stream>>>(out, rowmax, rowsum);
    scale_kernel<<<dim3(64, 16), 256, 0, stream>>>(out, rowsum);
}